// Round 6
// baseline (5237.127 us; speedup 1.0000x reference)
//
#include <hip/hip_runtime.h>
#include <hip/hip_bf16.h>
#include <hip/hip_cooperative_groups.h>

namespace cg = cooperative_groups;

#define DMODEL 512
#define NB 8
#define VOCABSZ 2048
#define MEL 80
#define DIN 1024
#define NSTATE 16
#define BATCH 4
#define TIN 2048
#define LL1 1024
#define LSEQ 512
#define MROWS (BATCH*LSEQ)    // 2048
#define M1ROWS (BATCH*LL1)    // 4096
#define NCHUNK 16
#define LCHUNK 32

typedef unsigned short u16;
typedef unsigned int   u32;
typedef __attribute__((ext_vector_type(8))) short short8;
typedef __attribute__((ext_vector_type(4))) float f32x4;

__device__ __forceinline__ float bf2f(u16 v) { return __uint_as_float(((u32)v) << 16); }
__device__ __forceinline__ u16 f2bf(float f) {
    u32 u = __float_as_uint(f);
    return (u16)((u + 0x7fffu + ((u >> 16) & 1u)) >> 16);
}
__device__ __forceinline__ float gelu_exact(float v) {
    return 0.5f * v * (1.0f + erff(v * 0.70710678118654752f));
}
__device__ __forceinline__ float silu_f(float v) { return v / (1.0f + __expf(-v)); }
__device__ __forceinline__ float softplus_f(float v) { return v > 20.f ? v : log1pf(__expf(v)); }

struct SmemGemm { u16 As[2][2048]; u16 Bs[2][2048]; };          // 16 KB
struct SmemScan { float bc[1024]; float dl[2048]; float xs[2048]; float z[2048]; }; // 28 KB
struct SmemT    { float tr[32][33]; };
union Smem { SmemGemm g; SmemScan s; SmemT t; };

__device__ __forceinline__ void gl_lds16(const u16* gp, u16* lp) {
    __builtin_amdgcn_global_load_lds(
        (const __attribute__((address_space(1))) void*)gp,
        (__attribute__((address_space(3))) void*)lp, 16, 0, 0);
}
__device__ __forceinline__ f32x4 mfma16(short8 a, short8 b, f32x4 c) {
    return __builtin_amdgcn_mfma_f32_16x16x32_bf16(a, b, c, 0, 0, 0);
}

struct KP {
    const float* feats; const int* flens;
    const float *c1b, *c2b, *nw, *cw, *cb, *dpb, *alog, *dskp, *hb;
    const float *c1w, *c2w, *ipw, *xpw, *dpw, *opw, *hw;
    u16 *XZb, *XN, *XSb, *DELb, *dtb, *Yb;
    u16 *ipwTa, *opwTa, *hwT, *xpwT, *dpwT, *c1wb, *c2wb, *Y1b;
    float *X, *XDB, *P, *Q;
    float* logits;
};

// ---------------------------------------------------------------------------
// Grid-stride GEMM stage: 64x64 tiles, BK=32, 2-phase dbuf, 4 waves (WM=WN=2).
// C = epi(A[M,K] @ BT[N,K]^T). EPI: 0 none,1 +bias,2 gelu,3 softplus,4 +=Cf,
// 5 xpj-special (Cf=XDB ldc 64; cols<32 also -> Cb bf16 ld 32).
// ---------------------------------------------------------------------------
template<int EPI>
__device__ void gemm_stage(Smem& sm, int ntiles, int ntx,
    const u16* __restrict__ A, int lda, const u16* __restrict__ BT, int ldb,
    const float* __restrict__ bias, float* __restrict__ Cf, u16* __restrict__ Cb,
    int ldc, int K)
{
    const int tid = threadIdx.x, lane = tid & 63, wave = tid >> 6;
    const int wm = wave >> 1, wn = wave & 1, lr = lane & 15, lk = lane >> 4;
    for (int tile = blockIdx.x; tile < ntiles; tile += gridDim.x) {
        const int m0 = (tile / ntx) * 64, n0 = (tile % ntx) * 64;
        f32x4 acc[2][2];
        acc[0][0] = acc[0][1] = acc[1][0] = acc[1][1] = (f32x4){0.f, 0.f, 0.f, 0.f};
        __syncthreads();
        gl_lds16(A  + (size_t)(m0 + (tid >> 2)) * lda + (tid & 3) * 8, &sm.g.As[0][tid * 8]);
        gl_lds16(BT + (size_t)(n0 + (tid >> 2)) * ldb + (tid & 3) * 8, &sm.g.Bs[0][tid * 8]);
        __syncthreads();
        int cur = 0;
        for (int kt = 0; kt < K; kt += 32) {
            if (kt + 32 < K) {
                gl_lds16(A  + (size_t)(m0 + (tid >> 2)) * lda + kt + 32 + (tid & 3) * 8,
                         &sm.g.As[cur ^ 1][tid * 8]);
                gl_lds16(BT + (size_t)(n0 + (tid >> 2)) * ldb + kt + 32 + (tid & 3) * 8,
                         &sm.g.Bs[cur ^ 1][tid * 8]);
            }
            short8 a0 = *(const short8*)&sm.g.As[cur][((wm * 2 + 0) * 16 + lr) * 32 + lk * 8];
            short8 a1 = *(const short8*)&sm.g.As[cur][((wm * 2 + 1) * 16 + lr) * 32 + lk * 8];
            short8 b0 = *(const short8*)&sm.g.Bs[cur][((wn * 2 + 0) * 16 + lr) * 32 + lk * 8];
            short8 b1 = *(const short8*)&sm.g.Bs[cur][((wn * 2 + 1) * 16 + lr) * 32 + lk * 8];
            acc[0][0] = mfma16(a0, b0, acc[0][0]);
            acc[0][1] = mfma16(a0, b1, acc[0][1]);
            acc[1][0] = mfma16(a1, b0, acc[1][0]);
            acc[1][1] = mfma16(a1, b1, acc[1][1]);
            __syncthreads();
            cur ^= 1;
        }
#pragma unroll
        for (int m = 0; m < 2; ++m) {
#pragma unroll
            for (int n = 0; n < 2; ++n) {
#pragma unroll
                for (int r = 0; r < 4; ++r) {
                    const int row = m0 + (wm * 2 + m) * 16 + lk * 4 + r;
                    const int col = n0 + (wn * 2 + n) * 16 + lr;
                    float v = acc[m][n][r];
                    if (EPI == 1)      v += bias[col];
                    else if (EPI == 2) v = gelu_exact(v + bias[col]);
                    else if (EPI == 3) v = softplus_f(v + bias[col]);
                    else if (EPI == 4) v += Cf[(size_t)row * ldc + col];
                    if (EPI == 5) {
                        Cf[(size_t)row * 64 + col] = v;
                        if (col < 32) Cb[(size_t)row * 32 + col] = f2bf(v);
                    } else {
                        if (Cf) Cf[(size_t)row * ldc + col] = v;
                        if (Cb) Cb[(size_t)row * ldc + col] = f2bf(v);
                    }
                }
            }
        }
    }
}

__device__ void castpad_stage(const float* __restrict__ in, u16* __restrict__ out,
                              int rows, int cin, int cout, int instride)
{
    const int gs = gridDim.x * 256;
    const int total = rows * cout;
    for (int idx = blockIdx.x * 256 + threadIdx.x; idx < total; idx += gs) {
        int c = idx % cout, r = idx / cout;
        out[idx] = (c < cin) ? f2bf(in[(size_t)r * instride + c]) : (u16)0;
    }
}

__device__ void tcast_stage(Smem& sm, const float* __restrict__ in, u16* __restrict__ out,
                            int R, int C, int nz, size_t sin, size_t sout)
{
    const int tx = threadIdx.x & 31, ty = threadIdx.x >> 5;
    const int tR = R / 32, tC = C / 32, per = tR * tC, nt = per * nz;
    for (int t0 = blockIdx.x; t0 < nt; t0 += gridDim.x) {
        const int z = t0 / per, rem = t0 % per;
        const int r0 = (rem / tC) * 32, c0 = (rem % tC) * 32;
        const float* ip = in + (size_t)z * sin;
        u16* op = out + (size_t)z * sout;
        __syncthreads();
#pragma unroll
        for (int i = 0; i < 4; ++i)
            sm.t.tr[ty + i * 8][tx] = ip[(size_t)(r0 + ty + i * 8) * C + c0 + tx];
        __syncthreads();
#pragma unroll
        for (int i = 0; i < 4; ++i)
            op[(size_t)(c0 + ty + i * 8) * R + r0 + tx] = f2bf(sm.t.tr[tx][ty + i * 8]);
    }
}

__device__ void im2col1_stage(const float* __restrict__ feats, u16* __restrict__ out)
{
    const int gs = gridDim.x * 256;
    for (int idx = blockIdx.x * 256 + threadIdx.x; idx < M1ROWS * 256; idx += gs) {
        int c = idx & 255, m = idx >> 8;
        int l1 = m & (LL1 - 1), b = m >> 10;
        float v = 0.f;
        if (c < 240) {
            int ci = c / 3, kk = c - ci * 3;
            int t = 2 * l1 - 1 + kk;
            if (t >= 0 && t < TIN) v = feats[((size_t)b * TIN + t) * MEL + ci];
        }
        out[idx] = f2bf(v);
    }
}

__device__ void im2col2_stage(const u16* __restrict__ y1b, u16* __restrict__ out)
{
    const int gs = gridDim.x * 256;
    for (int idx = blockIdx.x * 256 + threadIdx.x; idx < MROWS * 1536; idx += gs) {
        int c = idx % 1536, m = idx / 1536;
        int l = m & (LSEQ - 1), b = m >> 9;
        int ci = c / 3, kk = c - ci * 3;
        int t = 2 * l - 1 + kk;
        out[idx] = (t >= 0 && t < LL1) ? y1b[((size_t)b * LL1 + t) * 512 + ci] : (u16)0;
    }
}

__device__ void rmsnorm_stage(const float* __restrict__ X, const float* __restrict__ nw,
                              u16* __restrict__ XN)
{
    const int lane = threadIdx.x & 63;
    const int wtot = gridDim.x * 4;
    for (int row = blockIdx.x * 4 + (threadIdx.x >> 6); row < MROWS; row += wtot) {
        const float4 v0 = *(const float4*)&X[(size_t)row * 512 + lane * 8];
        const float4 v1 = *(const float4*)&X[(size_t)row * 512 + lane * 8 + 4];
        float ss = v0.x * v0.x + v0.y * v0.y + v0.z * v0.z + v0.w * v0.w
                 + v1.x * v1.x + v1.y * v1.y + v1.z * v1.z + v1.w * v1.w;
#pragma unroll
        for (int o = 1; o < 64; o <<= 1) ss += __shfl_xor(ss, o);
        const float sc = rsqrtf(ss * (1.f / 512.f) + 1e-5f);
        const float4 w0 = *(const float4*)&nw[lane * 8];
        const float4 w1 = *(const float4*)&nw[lane * 8 + 4];
        uint4 o4;
        o4.x = (u32)f2bf(v0.x * sc * w0.x) | ((u32)f2bf(v0.y * sc * w0.y) << 16);
        o4.y = (u32)f2bf(v0.z * sc * w0.z) | ((u32)f2bf(v0.w * sc * w0.w) << 16);
        o4.z = (u32)f2bf(v1.x * sc * w1.x) | ((u32)f2bf(v1.y * sc * w1.y) << 16);
        o4.w = (u32)f2bf(v1.z * sc * w1.z) | ((u32)f2bf(v1.w * sc * w1.w) << 16);
        *(uint4*)&XN[(size_t)row * 512 + lane * 8] = o4;
    }
}

__device__ void dwconv_stage(const u16* __restrict__ xzb, const float* __restrict__ cw,
                             const float* __restrict__ cb, u16* __restrict__ xsb)
{
    const int gs = gridDim.x * 256;
    for (int i = blockIdx.x * 256 + threadIdx.x; i < MROWS * DIN; i += gs) {
        int d = i & (DIN - 1), m = i >> 10;
        int l = m & (LSEQ - 1), b = m >> 9;
        float acc = cb[d];
        const float4 w4 = *(const float4*)&cw[d * 4];
        const float wk[4] = {w4.x, w4.y, w4.z, w4.w};
#pragma unroll
        for (int k = 0; k < 4; k++) {
            int t = l - 3 + k;
            if (t >= 0) acc += wk[k] * bf2f(xzb[((size_t)(b * LSEQ + t)) * (2 * DIN) + d]);
        }
        xsb[(size_t)m * DIN + d] = f2bf(silu_f(acc));
    }
}

template<int PASS>
__device__ void scan_stage(Smem& sm, const KP& p, int blk)
{
    const float* alog = p.alog + (size_t)blk * DIN * NSTATE;
    const float* dsk  = p.dskp + blk * DIN;
    const int tid = threadIdx.x, j = tid & 3, dsub = tid >> 2;
    for (int tile = blockIdx.x; tile < 1024; tile += gridDim.x) {
        const int b = tile >> 8, c = (tile >> 4) & 15, d0 = (tile & 15) * 64;
        const int d = d0 + dsub;
        const size_t rbase = (size_t)b * LSEQ + c * LCHUNK;
        __syncthreads();
        for (int idx = tid; idx < LCHUNK * 32; idx += 256) {
            int t = idx >> 5, cc = idx & 31;
            sm.s.bc[idx] = p.XDB[(rbase + t) * 64 + 32 + cc];
        }
        for (int idx = tid; idx < LCHUNK * 64; idx += 256) {
            int t = idx >> 6, dd = idx & 63;
            sm.s.dl[idx] = bf2f(p.DELb[(rbase + t) * DIN + d0 + dd]);
            sm.s.xs[idx] = bf2f(p.XSb[(rbase + t) * DIN + d0 + dd]);
            if (PASS) sm.s.z[idx] = bf2f(p.XZb[(rbase + t) * (2 * DIN) + DIN + d0 + dd]);
        }
        __syncthreads();
        float a[4], h[4];
#pragma unroll
        for (int nj = 0; nj < 4; nj++) {
            a[nj] = -__expf(alog[(size_t)d * NSTATE + j * 4 + nj]);
            h[nj] = 0.f;
        }
        const size_t chstride = (size_t)DIN * NSTATE;
        const size_t chcol = (size_t)d * NSTATE + j * 4;
        if (PASS) {
            for (int c2 = 0; c2 < c; ++c2) {
                const size_t o = ((size_t)(b * NCHUNK + c2)) * chstride + chcol;
                const float4 Pv = *(const float4*)&p.P[o];
                const float4 Qv = *(const float4*)&p.Q[o];
                h[0] = fmaf(Pv.x, h[0], Qv.x);
                h[1] = fmaf(Pv.y, h[1], Qv.y);
                h[2] = fmaf(Pv.z, h[2], Qv.z);
                h[3] = fmaf(Pv.w, h[3], Qv.w);
            }
        }
        const float dskv = PASS ? dsk[d] : 0.f;
        float sdl = 0.f;
        for (int t = 0; t < LCHUNK; t++) {
            const float dl = sm.s.dl[t * 64 + dsub];
            const float xv = sm.s.xs[t * 64 + dsub];
            const float dlx = dl * xv;
            if (!PASS) sdl += dl;
            float yv = 0.f;
#pragma unroll
            for (int nj = 0; nj < 4; nj++) {
                const float bn = sm.s.bc[t * 32 + j * 4 + nj];
                const float dA = __expf(dl * a[nj]);
                h[nj] = fmaf(dA, h[nj], dlx * bn);
                if (PASS) {
                    const float cn = sm.s.bc[t * 32 + 16 + j * 4 + nj];
                    yv = fmaf(h[nj], cn, yv);
                }
            }
            if (PASS) {
                yv += __shfl_xor(yv, 1);
                yv += __shfl_xor(yv, 2);
                if (j == 0) {
                    const float zv = sm.s.z[t * 64 + dsub];
                    p.Yb[(rbase + t) * DIN + d] = f2bf((yv + xv * dskv) * silu_f(zv));
                }
            }
        }
        if (!PASS) {
            const size_t o = ((size_t)(b * NCHUNK + c)) * chstride + chcol;
            float4 Pv, Qv;
            Pv.x = __expf(a[0] * sdl); Pv.y = __expf(a[1] * sdl);
            Pv.z = __expf(a[2] * sdl); Pv.w = __expf(a[3] * sdl);
            Qv.x = h[0]; Qv.y = h[1]; Qv.z = h[2]; Qv.w = h[3];
            *(float4*)&p.P[o] = Pv;
            *(float4*)&p.Q[o] = Qv;
        }
    }
}

// ---------------------------------------------------------------------------
// The megakernel.
// ---------------------------------------------------------------------------
__global__ __launch_bounds__(256, 4) void mega_k(KP p)
{
    __shared__ Smem sm;
    cg::grid_group grid = cg::this_grid();

    // ---- weight prep ----
    castpad_stage(p.c1w, p.c1wb, 512, 240, 256, 240);
    castpad_stage(p.c2w, p.c2wb, 512, 1536, 1536, 1536);
    tcast_stage(sm, p.hw,  p.hwT,  512, 2048, 1, 0, 0);
    tcast_stage(sm, p.xpw, p.xpwT, 1024, 64, 8, 65536, 65536);
    tcast_stage(sm, p.dpw, p.dpwT, 32, 1024, 8, 32768, 32768);
    tcast_stage(sm, p.ipw, p.ipwTa, 512, 2048, 8, 1048576, 1048576);
    tcast_stage(sm, p.opw, p.opwTa, 1024, 512, 8, 524288, 524288);
    grid.sync();

    // ---- frontend ----
    im2col1_stage(p.feats, p.XZb);
    grid.sync();
    gemm_stage<2>(sm, 512, 8, p.XZb, 256, p.c1wb, 256, p.c1b, nullptr, p.Y1b, 512, 256);
    grid.sync();
    im2col2_stage(p.Y1b, p.XZb);
    grid.sync();
    gemm_stage<2>(sm, 256, 8, p.XZb, 1536, p.c2wb, 1536, p.c2b, p.X, nullptr, 512, 1536);
    grid.sync();

    // ---- mamba blocks ----
    for (int blk = 0; blk < NB; ++blk) {
        rmsnorm_stage(p.X, p.nw + blk * DMODEL, p.XN);
        grid.sync();
        // in_proj (2048,2048,512) -> XZb bf16
        gemm_stage<0>(sm, 1024, 32, p.XN, 512, p.ipwTa + (size_t)blk * 1048576, 512,
                      nullptr, nullptr, p.XZb, 2048, 512);
        grid.sync();
        dwconv_stage(p.XZb, p.cw + blk * DIN * 4, p.cb + blk * DIN, p.XSb);
        grid.sync();
        // x_proj (2048,64,1024) -> XDB f32 + dtb bf16 (cols<32)
        gemm_stage<5>(sm, 32, 1, p.XSb, 1024, p.xpwT + (size_t)blk * 65536, 1024,
                      nullptr, p.XDB, p.dtb, 64, 1024);
        grid.sync();
        // dt_proj (2048,1024,32) + softplus -> DELb bf16
        gemm_stage<3>(sm, 512, 16, p.dtb, 32, p.dpwT + (size_t)blk * 32768, 32,
                      p.dpb + blk * DIN, nullptr, p.DELb, 1024, 32);
        grid.sync();
        scan_stage<0>(sm, p, blk);
        grid.sync();
        scan_stage<1>(sm, p, blk);
        grid.sync();
        // out_proj (2048,512,1024) + residual -> X f32 (+ XN bf16 on last layer)
        gemm_stage<4>(sm, 256, 8, p.Yb, 1024, p.opwTa + (size_t)blk * 524288, 1024,
                      nullptr, p.X, (blk == NB - 1) ? p.XN : nullptr, 512, 1024);
        grid.sync();
    }

    // ---- head ----
    if (blockIdx.x == 0 && threadIdx.x < BATCH) {
        int v = p.flens[threadIdx.x] / 4;
        if (v < 1) v = 1;
        p.logits[(size_t)MROWS * VOCABSZ + threadIdx.x] = (float)v;
    }
    gemm_stage<1>(sm, 1024, 32, p.XN, 512, p.hwT, 512, p.hb, p.logits, nullptr, 2048, 512);
}

extern "C" void kernel_launch(void* const* d_in, const int* in_sizes, int n_in,
                              void* d_out, int out_size, void* d_ws, size_t ws_size,
                              hipStream_t stream)
{
    float* ws = (float*)d_ws;
    KP p;
    p.feats = (const float*)d_in[0];
    p.flens = (const int*)  d_in[1];
    p.c1w = (const float*)d_in[2];
    p.c1b = (const float*)d_in[3];
    p.c2w = (const float*)d_in[4];
    p.c2b = (const float*)d_in[5];
    p.nw  = (const float*)d_in[6];
    p.ipw = (const float*)d_in[7];
    p.cw  = (const float*)d_in[8];
    p.cb  = (const float*)d_in[9];
    p.xpw = (const float*)d_in[10];
    p.dpw = (const float*)d_in[11];
    p.dpb = (const float*)d_in[12];
    p.alog= (const float*)d_in[13];
    p.dskp= (const float*)d_in[14];
    p.opw = (const float*)d_in[15];
    p.hw  = (const float*)d_in[16];
    p.hb  = (const float*)d_in[17];

    p.XZb   = (u16*)ws;                  // 2,097,152 f
    p.X     = ws + 2097152;              // 1,048,576 f
    p.XN    = (u16*)(ws + 3145728);      //   524,288 f
    p.XSb   = (u16*)(ws + 3670016);      // 1,048,576 f
    p.DELb  = (u16*)(ws + 4718592);      // 1,048,576 f
    p.XDB   = ws + 5767168;              //   131,072 f
    p.P     = ws + 5898240;              // 1,048,576 f
    p.dtb   = (u16*)(ws + 6946816);      //    32,768 f
    p.Yb    = (u16*)(ws + 6979584);      // 1,048,576 f
    p.ipwTa = (u16*)(ws + 8028160);      // 4,194,304 f
    p.opwTa = (u16*)(ws + 12222464);     // 2,097,152 f
    p.hwT   = (u16*)(ws + 14319616);     //   524,288 f
    p.xpwT  = (u16*)(ws + 14843904);     //   262,144 f
    p.dpwT  = (u16*)(ws + 15106048);     //   131,072 f
    p.c1wb  = (u16*)(ws + 15237120);     //    65,536 f
    p.c2wb  = (u16*)(ws + 15302656);     //   393,216 f
    p.Y1b   = (u16*)(ws + 15695872);     // 1,048,576 f (frontend only)
    p.Q     = ws + 15695872;             // aliases Y1b (layers only)
    p.logits = (float*)d_out;

    int mbpc = 0;
    hipOccupancyMaxActiveBlocksPerMultiprocessor(&mbpc, mega_k, 256, 0);
    int nblk = 1024;
    if (mbpc < 4) nblk = (mbpc >= 2) ? 512 : 256;

    void* kargs[] = { (void*)&p };
    hipLaunchCooperativeKernel(mega_k, dim3(nblk), dim3(256), kargs, 0, stream);
}

// Round 7
// 1011.300 us; speedup vs baseline: 5.1786x; 5.1786x over previous
//
#include <hip/hip_runtime.h>
#include <hip/hip_bf16.h>

#define DMODEL 512
#define NB 8
#define VOCABSZ 2048
#define MEL 80
#define DIN 1024
#define NSTATE 16
#define BATCH 4
#define TIN 2048
#define LL1 1024
#define LSEQ 512
#define MROWS (BATCH*LSEQ)    // 2048
#define M1ROWS (BATCH*LL1)    // 4096
#define NCHUNK 16
#define LCHUNK 32

typedef unsigned short u16;
typedef unsigned int   u32;
typedef __attribute__((ext_vector_type(8))) short short8;
typedef __attribute__((ext_vector_type(4))) float f32x4;

__device__ __forceinline__ float bf2f(u16 v) { return __uint_as_float(((u32)v) << 16); }
__device__ __forceinline__ u16 f2bf(float f) {
    u32 u = __float_as_uint(f);
    return (u16)((u + 0x7fffu + ((u >> 16) & 1u)) >> 16);
}
__device__ __forceinline__ float gelu_exact(float v) {
    return 0.5f * v * (1.0f + erff(v * 0.70710678118654752f));
}
__device__ __forceinline__ float silu_f(float v) { return v / (1.0f + __expf(-v)); }
__device__ __forceinline__ float softplus_f(float v) { return v > 20.f ? v : log1pf(__expf(v)); }

// ---------------------------------------------------------------------------
// bf16 MFMA GEMM, 2-phase double-buffered LDS (R5-proven).
// C[M,N] = epi(A[M,K] @ BT[N,K]^T + bias).  BM=WM*MR*16, BN=WN*NR*16, BK=32.
// EPI: 0 none, 1 +bias, 2 gelu(+bias), 3 softplus(+bias), 4 +=Cf residual
// SPLITK>1: blockIdx.z owns K/SPLITK slice, writes Cf + z*zstride (EPI 0).
// ---------------------------------------------------------------------------
template<int WM, int WN, int MR, int NR, int EPI, int SPLITK>
__global__ __launch_bounds__(WM*WN*64) void gemm2_bf16(
    const u16* __restrict__ A, int lda,
    const u16* __restrict__ BT, int ldb,
    const float* __restrict__ bias,
    float* __restrict__ Cf, u16* __restrict__ Cb, int ldc,
    int K, int zstride)
{
    constexpr int BM = WM * MR * 16;
    constexpr int BN = WN * NR * 16;
    constexpr int NT = WM * WN * 64;
    constexpr int LA = (BM * 4) / NT;
    constexpr int LB = (BN * 4) / NT;
    __shared__ __align__(16) u16 As[2][BM * 32];
    __shared__ __align__(16) u16 Bs[2][BN * 32];
    const int tid = threadIdx.x;
    const int m0 = blockIdx.y * BM, n0 = blockIdx.x * BN;
    const int lane = tid & 63;
    const int wave = tid >> 6;
    const int wm = wave / WN, wn = wave % WN;
    const int lr = lane & 15, lk = lane >> 4;

    int kt0 = 0, kend = K;
    if (SPLITK > 1) {
        const int kb = K / SPLITK;
        kt0 = blockIdx.z * kb;
        kend = kt0 + kb;
        Cf += (size_t)blockIdx.z * zstride;
    }

    f32x4 acc[MR][NR];
#pragma unroll
    for (int m = 0; m < MR; ++m)
#pragma unroll
        for (int n = 0; n < NR; ++n) acc[m][n] = (f32x4){0.f, 0.f, 0.f, 0.f};

    auto stage = [&](int buf, int kt) {
#pragma unroll
        for (int c = 0; c < LA; ++c) {
            int idx = c * NT + tid;
            const u16* src = A + (size_t)(m0 + (idx >> 2)) * lda + kt + (idx & 3) * 8;
            __builtin_amdgcn_global_load_lds(
                (const __attribute__((address_space(1))) void*)src,
                (__attribute__((address_space(3))) void*)&As[buf][idx * 8], 16, 0, 0);
        }
#pragma unroll
        for (int c = 0; c < LB; ++c) {
            int idx = c * NT + tid;
            const u16* src = BT + (size_t)(n0 + (idx >> 2)) * ldb + kt + (idx & 3) * 8;
            __builtin_amdgcn_global_load_lds(
                (const __attribute__((address_space(1))) void*)src,
                (__attribute__((address_space(3))) void*)&Bs[buf][idx * 8], 16, 0, 0);
        }
    };

    stage(0, kt0);
    __syncthreads();
    int cur = 0;
    for (int kt = kt0; kt < kend; kt += 32) {
        if (kt + 32 < kend) stage(cur ^ 1, kt + 32);
        short8 a[MR], b[NR];
#pragma unroll
        for (int m = 0; m < MR; ++m)
            a[m] = *(const short8*)&As[cur][((wm * MR + m) * 16 + lr) * 32 + lk * 8];
#pragma unroll
        for (int n = 0; n < NR; ++n)
            b[n] = *(const short8*)&Bs[cur][((wn * NR + n) * 16 + lr) * 32 + lk * 8];
#pragma unroll
        for (int m = 0; m < MR; ++m)
#pragma unroll
            for (int n = 0; n < NR; ++n)
                acc[m][n] = __builtin_amdgcn_mfma_f32_16x16x32_bf16(a[m], b[n], acc[m][n], 0, 0, 0);
        __syncthreads();
        cur ^= 1;
    }

#pragma unroll
    for (int m = 0; m < MR; ++m) {
#pragma unroll
        for (int n = 0; n < NR; ++n) {
#pragma unroll
            for (int r = 0; r < 4; ++r) {
                const int row = m0 + (wm * MR + m) * 16 + lk * 4 + r;
                const int col = n0 + (wn * NR + n) * 16 + lr;
                float v = acc[m][n][r];
                if (EPI == 1)      v += bias[col];
                else if (EPI == 2) v = gelu_exact(v + bias[col]);
                else if (EPI == 3) v = softplus_f(v + bias[col]);
                else if (EPI == 4) v += Cf[(size_t)row * ldc + col];
                if (Cf) Cf[(size_t)row * ldc + col] = v;
                if (Cb) Cb[(size_t)row * ldc + col] = f2bf(v);
            }
        }
    }
}

// transpose-cast: in (R,C) fp32 -> out (C,R) bf16; batched over blockIdx.z
__global__ __launch_bounds__(256) void tcast_k(const float* __restrict__ in, u16* __restrict__ out,
                                               int R, int C, size_t sin, size_t sout) {
    in  += (size_t)blockIdx.z * sin;
    out += (size_t)blockIdx.z * sout;
    __shared__ float s[32][33];
    const int tx = threadIdx.x & 31, ty = threadIdx.x >> 5;
    const int r0 = blockIdx.y * 32, c0 = blockIdx.x * 32;
#pragma unroll
    for (int i = 0; i < 4; ++i)
        s[ty + i * 8][tx] = in[(size_t)(r0 + ty + i * 8) * C + c0 + tx];
    __syncthreads();
#pragma unroll
    for (int i = 0; i < 4; ++i)
        out[(size_t)(c0 + ty + i * 8) * R + r0 + tx] = f2bf(s[tx][ty + i * 8]);
}

// strided cast+pad: out[r][c] = c<cin ? in[r*instride+c] : 0
__global__ void castpad_k(const float* __restrict__ in, u16* __restrict__ out,
                          int rows, int cin, int cout, int instride,
                          size_t sin, size_t sout) {
    in  += (size_t)blockIdx.z * sin;
    out += (size_t)blockIdx.z * sout;
    int idx = blockIdx.x * 256 + threadIdx.x;
    if (idx >= rows * cout) return;
    int c = idx % cout, r = idx / cout;
    out[idx] = (c < cin) ? f2bf(in[(size_t)r * instride + c]) : (u16)0;
}

// im2col for conv1 -> bf16, K padded 240->256; also writes out_lens (once)
__global__ void im2col1_k(const float* __restrict__ feats, u16* __restrict__ out,
                          const int* __restrict__ feat_lens, float* __restrict__ lens_out) {
    int idx = blockIdx.x * 256 + threadIdx.x;       // M1ROWS*256
    if (blockIdx.x == 0 && threadIdx.x < BATCH) {
        int v = feat_lens[threadIdx.x] / 4;
        if (v < 1) v = 1;
        lens_out[threadIdx.x] = (float)v;
    }
    int c = idx & 255, m = idx >> 8;
    int l1 = m & (LL1 - 1), b = m >> 10;
    float v = 0.f;
    if (c < 240) {
        int ci = c / 3, kk = c - ci * 3;
        int t = 2 * l1 - 1 + kk;
        if (t >= 0 && t < TIN) v = feats[((size_t)b * TIN + t) * MEL + ci];
    }
    out[idx] = f2bf(v);
}

// im2col for conv2: bf16 in (Y1b), bf16 out (2048,1536)
__global__ void im2col2_k(const u16* __restrict__ y1b, u16* __restrict__ out) {
    int idx = blockIdx.x * 256 + threadIdx.x;       // MROWS*1536
    int c = idx % 1536, m = idx / 1536;
    int l = m & (LSEQ - 1), b = m >> 9;
    int ci = c / 3, kk = c - ci * 3;
    int t = 2 * l - 1 + kk;
    out[idx] = (t >= 0 && t < LL1) ? y1b[((size_t)b * LL1 + t) * 512 + ci] : (u16)0;
}

// RMSNorm: one block per row of 512; fp32 in, bf16 out
__global__ __launch_bounds__(256) void rmsnorm_k(const float* __restrict__ x,
                                                 const float* __restrict__ nw,
                                                 u16* __restrict__ xn) {
    int m = blockIdx.x;
    int tid = threadIdx.x;
    const float2 v = *reinterpret_cast<const float2*>(&x[(size_t)m * DMODEL + tid * 2]);
    float ss = v.x * v.x + v.y * v.y;
#pragma unroll
    for (int o = 32; o > 0; o >>= 1) ss += __shfl_down(ss, o);
    __shared__ float sred[4];
    __shared__ float sscale;
    if ((tid & 63) == 0) sred[tid >> 6] = ss;
    __syncthreads();
    if (tid == 0) {
        float tot = sred[0] + sred[1] + sred[2] + sred[3];
        sscale = rsqrtf(tot / 512.f + 1e-5f);
    }
    __syncthreads();
    float sc = sscale;
    u32 pack = (u32)f2bf(v.x * sc * nw[tid * 2]) | ((u32)f2bf(v.y * sc * nw[tid * 2 + 1]) << 16);
    *reinterpret_cast<u32*>(&xn[(size_t)m * DMODEL + tid * 2]) = pack;
}

// causal depthwise conv (K=4) + bias + SiLU; bf16 in, bf16 out
__global__ __launch_bounds__(256) void dwconv_silu_k(const u16* __restrict__ xzb,
                                                     const float* __restrict__ cw,
                                                     const float* __restrict__ cb,
                                                     u16* __restrict__ xsb) {
    int d = blockIdx.x * 256 + threadIdx.x;
    int m = blockIdx.y;
    int l = m & (LSEQ - 1);
    int b = m >> 9;
    float acc = cb[d];
    const float4 w4 = *reinterpret_cast<const float4*>(&cw[d * 4]);
    const float wk[4] = {w4.x, w4.y, w4.z, w4.w};
#pragma unroll
    for (int k = 0; k < 4; k++) {
        int t = l - 3 + k;
        if (t >= 0) acc += wk[k] * bf2f(xzb[((size_t)(b * LSEQ + t)) * (2 * DIN) + d]);
    }
    xsb[(size_t)m * DIN + d] = f2bf(silu_f(acc));
}

// ---------------------------------------------------------------------------
// Fused split-K reduce + dt_proj + softplus.
// Block = 16 rows. Stage: sum 4 partials -> dt_lds (cols 0..31 f32) and
// XDB (cols 32..63, global f32). Then DELb[r][dcol] =
// softplus(sum_k dt[r][k]*dpw[dcol][k] + dpb[dcol]) via VALU (K=32).
// ---------------------------------------------------------------------------
__global__ __launch_bounds__(256) void xdt_k(const float* __restrict__ part,
                                             const u16* __restrict__ dpwT,
                                             const float* __restrict__ dpb,
                                             float* __restrict__ xdb,
                                             u16* __restrict__ delb) {
    __shared__ float dt_lds[16][32];
    const int tid = threadIdx.x;
    const int r0 = blockIdx.x * 16;
#pragma unroll
    for (int half = 0; half < 2; ++half) {
        int idx = half * 256 + tid;                 // 0..511 over 16x32
        int r = idx >> 5, c = idx & 31;
        size_t o = (size_t)(r0 + r) * 64 + c;
        float dtv = part[o] + part[131072 + o] + part[262144 + o] + part[393216 + o];
        dt_lds[r][c] = dtv;
        size_t o2 = o + 32;
        float bcv = part[o2] + part[131072 + o2] + part[262144 + o2] + part[393216 + o2];
        xdb[(size_t)(r0 + r) * 64 + 32 + c] = bcv;
    }
    __syncthreads();
#pragma unroll
    for (int i = 0; i < 4; ++i) {
        const int dcol = i * 256 + tid;
        const uint4 w0 = *(const uint4*)&dpwT[dcol * 32];
        const uint4 w1 = *(const uint4*)&dpwT[dcol * 32 + 8];
        const uint4 w2 = *(const uint4*)&dpwT[dcol * 32 + 16];
        const uint4 w3 = *(const uint4*)&dpwT[dcol * 32 + 24];
        float wk[32];
        const u32 wa[16] = {w0.x, w0.y, w0.z, w0.w, w1.x, w1.y, w1.z, w1.w,
                            w2.x, w2.y, w2.z, w2.w, w3.x, w3.y, w3.z, w3.w};
#pragma unroll
        for (int k = 0; k < 16; ++k) {
            wk[2 * k]     = bf2f((u16)(wa[k] & 0xffffu));
            wk[2 * k + 1] = bf2f((u16)(wa[k] >> 16));
        }
        const float bias = dpb[dcol];
        for (int r = 0; r < 16; ++r) {
            float acc = bias;
#pragma unroll
            for (int k = 0; k < 32; ++k) acc = fmaf(dt_lds[r][k], wk[k], acc);
            delb[(size_t)(r0 + r) * DIN + dcol] = f2bf(softplus_f(acc));
        }
    }
}

// ---------------------------------------------------------------------------
// Chunked parallel scan (R5-proven).  PASS0: emit P,Q.  PASS1: combine prefix
// in-kernel, seeded scan, fused +xs*D and *silu(z) epilogue -> y bf16.
// ---------------------------------------------------------------------------
template<int PASS>
__global__ __launch_bounds__(256) void scan_chunk_k(
    const u16* __restrict__ deltab, const u16* __restrict__ xsb,
    const float* __restrict__ xdb, const u16* __restrict__ xzb,
    const float* __restrict__ alog, const float* __restrict__ dsk,
    float* __restrict__ P, float* __restrict__ Q,
    u16* __restrict__ yb)
{
    __shared__ float s_bc[LCHUNK * 32];
    __shared__ float s_dl[LCHUNK * 64];
    __shared__ float s_xs[LCHUNK * 64];
    __shared__ float s_z [PASS ? LCHUNK * 64 : 1];

    const int tid  = threadIdx.x;
    const int j    = tid & 3;
    const int dsub = tid >> 2;
    const int d0   = blockIdx.x * 64;
    const int c    = blockIdx.y;
    const int b    = blockIdx.z;
    const int d    = d0 + dsub;
    const size_t rbase = (size_t)b * LSEQ + c * LCHUNK;

    for (int idx = tid; idx < LCHUNK * 32; idx += 256) {
        int t = idx >> 5, cc = idx & 31;
        s_bc[idx] = xdb[(rbase + t) * 64 + 32 + cc];
    }
    for (int idx = tid; idx < LCHUNK * 64; idx += 256) {
        int t = idx >> 6, dd = idx & 63;
        s_dl[idx] = bf2f(deltab[(rbase + t) * DIN + d0 + dd]);
        s_xs[idx] = bf2f(xsb[(rbase + t) * DIN + d0 + dd]);
        if (PASS) s_z[idx] = bf2f(xzb[(rbase + t) * (2 * DIN) + DIN + d0 + dd]);
    }
    __syncthreads();

    float a[4], h[4];
#pragma unroll
    for (int nj = 0; nj < 4; nj++)
        a[nj] = -__expf(alog[(size_t)d * NSTATE + j * 4 + nj]);

    const size_t chstride = (size_t)DIN * NSTATE;
    const size_t chcol = (size_t)d * NSTATE + j * 4;
    h[0] = h[1] = h[2] = h[3] = 0.f;
    if (PASS) {
        for (int c2 = 0; c2 < c; ++c2) {
            const size_t o = ((size_t)(b * NCHUNK + c2)) * chstride + chcol;
            const float4 Pv = *(const float4*)&P[o];
            const float4 Qv = *(const float4*)&Q[o];
            h[0] = fmaf(Pv.x, h[0], Qv.x);
            h[1] = fmaf(Pv.y, h[1], Qv.y);
            h[2] = fmaf(Pv.z, h[2], Qv.z);
            h[3] = fmaf(Pv.w, h[3], Qv.w);
        }
    }
    const float dskv = PASS ? dsk[d] : 0.f;
    float sdl = 0.f;

    for (int t = 0; t < LCHUNK; t++) {
        const float dl = s_dl[t * 64 + dsub];
        const float xv = s_xs[t * 64 + dsub];
        const float dlx = dl * xv;
        if (!PASS) sdl += dl;
        float yv = 0.f;
#pragma unroll
        for (int nj = 0; nj < 4; nj++) {
            const float bn = s_bc[t * 32 + j * 4 + nj];
            const float dA = __expf(dl * a[nj]);
            h[nj] = fmaf(dA, h[nj], dlx * bn);
            if (PASS) {
                const float cn = s_bc[t * 32 + 16 + j * 4 + nj];
                yv = fmaf(h[nj], cn, yv);
            }
        }
        if (PASS) {
            yv += __shfl_xor(yv, 1);
            yv += __shfl_xor(yv, 2);
            if (j == 0) {
                const float zv = s_z[t * 64 + dsub];
                yb[(rbase + t) * DIN + d] = f2bf((yv + xv * dskv) * silu_f(zv));
            }
        }
    }

    if (!PASS) {
        const size_t o = ((size_t)(b * NCHUNK + c)) * chstride + chcol;
        float4 Pv, Qv;
        Pv.x = __expf(a[0] * sdl); Pv.y = __expf(a[1] * sdl);
        Pv.z = __expf(a[2] * sdl); Pv.w = __expf(a[3] * sdl);
        Qv.x = h[0]; Qv.y = h[1]; Qv.z = h[2]; Qv.w = h[3];
        *(float4*)&P[o] = Pv;
        *(float4*)&Q[o] = Qv;
    }
}

extern "C" void kernel_launch(void* const* d_in, const int* in_sizes, int n_in,
                              void* d_out, int out_size, void* d_ws, size_t ws_size,
                              hipStream_t stream)
{
    const float* feats = (const float*)d_in[0];
    const int*   flens = (const int*)  d_in[1];
    const float* c1w = (const float*)d_in[2];
    const float* c1b = (const float*)d_in[3];
    const float* c2w = (const float*)d_in[4];
    const float* c2b = (const float*)d_in[5];
    const float* nw  = (const float*)d_in[6];
    const float* ipw = (const float*)d_in[7];
    const float* cw  = (const float*)d_in[8];
    const float* cb  = (const float*)d_in[9];
    const float* xpw = (const float*)d_in[10];
    const float* dpw = (const float*)d_in[11];
    const float* dpb = (const float*)d_in[12];
    const float* alog= (const float*)d_in[13];
    const float* dskp= (const float*)d_in[14];
    const float* opw = (const float*)d_in[15];
    const float* hw  = (const float*)d_in[16];
    const float* hb  = (const float*)d_in[17];

    float* ws = (float*)d_ws;
    u16*  XZb    = (u16*)ws;                      // (2048,2048) bf16
    float* X     = ws + 2097152;                  // (2048,512) f32
    u16*  XN     = (u16*)(ws + 3145728);          // (2048,512) bf16
    u16*  Xb     = (u16*)(ws + 3670016);          // (2048,512) bf16
    u16*  XSb    = (u16*)(ws + 4194304);          // (2048,1024) bf16
    u16*  DELb   = (u16*)(ws + 5242880);          // (2048,1024) bf16
    float* XDB   = ws + 6291456;                  // (2048,64) f32
    float* P     = ws + 6422528;                  // (4,16,1024,16) f32
    u16*  Yb     = (u16*)(ws + 7503872);          // (2048,1024) bf16
    float* XDBp  = ws + 8552448;                  // 4 x (2048,64) f32
    u16*  ipwTa  = (u16*)(ws + 9076736);          // 8 x (2048,512) bf16
    u16*  opwTa  = (u16*)(ws + 13271040);         // 8 x (512,1024) bf16
    u16*  hwT    = (u16*)(ws + 15368192);         // (2048,512) bf16
    u16*  xpwT   = (u16*)(ws + 15892480);         // 8 x (64,1024) bf16
    u16*  dpwT   = (u16*)(ws + 16154624);         // 8 x (1024,32) bf16
    u16*  c1wb   = (u16*)(ws + 16285696);         // (512,256) bf16
    u16*  c2wb   = (u16*)(ws + 16351232);         // (512,1536) bf16
    u16*  Y1b    = (u16*)(ws + 16744448);         // (4096,512) bf16
    float* logits = (float*)d_out;
    float* Q     = logits;                        // 1M floats of d_out; head overwrites

    // ---------------- weight prep (once, batched) ----------------
    castpad_k<<<dim3(512, 1, 1), 256, 0, stream>>>(c1w, c1wb, 512, 240, 256, 240, 0, 0);
    castpad_k<<<dim3(3072, 1, 1), 256, 0, stream>>>(c2w, c2wb, 512, 1536, 1536, 1536, 0, 0);
    tcast_k<<<dim3(64, 16, 1), 256, 0, stream>>>(hw, hwT, 512, 2048, 0, 0);
    tcast_k<<<dim3(2, 32, 8), 256, 0, stream>>>(xpw, xpwT, 1024, 64, 65536, 65536);
    tcast_k<<<dim3(32, 1, 8), 256, 0, stream>>>(dpw, dpwT, 32, 1024, 32768, 32768);
    tcast_k<<<dim3(64, 16, 8), 256, 0, stream>>>(ipw, ipwTa, 512, 2048, 1048576, 1048576);
    tcast_k<<<dim3(16, 32, 8), 256, 0, stream>>>(opw, opwTa, 1024, 512, 524288, 524288);

    // ---------------- frontend ----------------
    im2col1_k<<<4096, 256, 0, stream>>>(feats, XZb, flens, logits + (size_t)MROWS * VOCABSZ);
    gemm2_bf16<2, 2, 4, 2, 2, 1><<<dim3(8, 32), 256, 0, stream>>>(
        XZb, 256, c1wb, 256, c1b, nullptr, Y1b, 512, 256, 0);
    im2col2_k<<<12288, 256, 0, stream>>>(Y1b, XZb);
    gemm2_bf16<2, 2, 2, 2, 2, 1><<<dim3(8, 32), 256, 0, stream>>>(
        XZb, 1536, c2wb, 1536, c2b, X, nullptr, 512, 1536, 0);

    // ---------------- mamba blocks ----------------
    for (int blk = 0; blk < NB; ++blk) {
        rmsnorm_k<<<MROWS, 256, 0, stream>>>(X, nw + blk * DMODEL, XN);
        // in_proj: (2048,2048,512), 128x128 tiles
        gemm2_bf16<2, 2, 4, 4, 0, 1><<<dim3(16, 16), 256, 0, stream>>>(
            XN, 512, ipwTa + (size_t)blk * 1048576, 512, nullptr,
            nullptr, XZb, 2048, 512, 0);
        dwconv_silu_k<<<dim3(4, MROWS), 256, 0, stream>>>(
            XZb, cw + blk * DIN * 4, cb + blk * DIN, XSb);
        // x_proj: (2048,64,1024) split-K x4
        gemm2_bf16<2, 2, 2, 2, 0, 4><<<dim3(1, 32, 4), 256, 0, stream>>>(
            XSb, 1024, xpwT + (size_t)blk * 65536, 1024, nullptr,
            XDBp, nullptr, 64, 1024, 131072);
        // fused reduce + dt_proj + softplus
        xdt_k<<<128, 256, 0, stream>>>(XDBp, dpwT + (size_t)blk * 32768,
                                       dpb + blk * DIN, XDB, DELb);
        // chunked parallel scan
        scan_chunk_k<0><<<dim3(16, NCHUNK, BATCH), 256, 0, stream>>>(
            DELb, XSb, XDB, nullptr, alog + (size_t)blk * DIN * NSTATE,
            nullptr, P, Q, nullptr);
        scan_chunk_k<1><<<dim3(16, NCHUNK, BATCH), 256, 0, stream>>>(
            DELb, XSb, XDB, XZb, alog + (size_t)blk * DIN * NSTATE,
            dskp + blk * DIN, P, Q, Yb);
        // out_proj: (2048,512,1024) + residual
        gemm2_bf16<2, 2, 2, 2, 4, 1><<<dim3(8, 32), 256, 0, stream>>>(
            Yb, 1024, opwTa + (size_t)blk * 524288, 1024, nullptr,
            X, Xb, 512, 1024, 0);
    }

    // ---------------- head: (2048,2048,512), 128x128 tiles ----------------
    gemm2_bf16<2, 2, 4, 4, 1, 1><<<dim3(16, 16), 256, 0, stream>>>(
        Xb, 512, hwT, 512, hb, logits, nullptr, 2048, 512, 0);
}

// Round 8
// 980.295 us; speedup vs baseline: 5.3424x; 1.0316x over previous
//
#include <hip/hip_runtime.h>
#include <hip/hip_bf16.h>

#define DMODEL 512
#define NB 8
#define VOCABSZ 2048
#define MEL 80
#define DIN 1024
#define NSTATE 16
#define BATCH 4
#define TIN 2048
#define LL1 1024
#define LSEQ 512
#define MROWS (BATCH*LSEQ)    // 2048
#define M1ROWS (BATCH*LL1)    // 4096
#define NCHUNK 16
#define LCHUNK 32

typedef unsigned short u16;
typedef unsigned int   u32;
typedef __attribute__((ext_vector_type(8))) short short8;
typedef __attribute__((ext_vector_type(4))) float f32x4;

__device__ __forceinline__ float bf2f(u16 v) { return __uint_as_float(((u32)v) << 16); }
__device__ __forceinline__ u16 f2bf(float f) {
    u32 u = __float_as_uint(f);
    return (u16)((u + 0x7fffu + ((u >> 16) & 1u)) >> 16);
}
__device__ __forceinline__ float gelu_exact(float v) {
    return 0.5f * v * (1.0f + erff(v * 0.70710678118654752f));
}
__device__ __forceinline__ float silu_f(float v) { return v / (1.0f + __expf(-v)); }
__device__ __forceinline__ float softplus_f(float v) { return v > 20.f ? v : log1pf(__expf(v)); }
__device__ __forceinline__ f32x4 mfma16(short8 a, short8 b, f32x4 c) {
    return __builtin_amdgcn_mfma_f32_16x16x32_bf16(a, b, c, 0, 0, 0);
}

// ---------------------------------------------------------------------------
// bf16 MFMA GEMM, 2-phase double-buffered LDS (R5-proven).
// ---------------------------------------------------------------------------
template<int WM, int WN, int MR, int NR, int EPI, int SPLITK>
__global__ __launch_bounds__(WM*WN*64) void gemm2_bf16(
    const u16* __restrict__ A, int lda,
    const u16* __restrict__ BT, int ldb,
    const float* __restrict__ bias,
    float* __restrict__ Cf, u16* __restrict__ Cb, int ldc,
    int K, int zstride)
{
    constexpr int BM = WM * MR * 16;
    constexpr int BN = WN * NR * 16;
    constexpr int NT = WM * WN * 64;
    constexpr int LA = (BM * 4) / NT;
    constexpr int LB = (BN * 4) / NT;
    __shared__ __align__(16) u16 As[2][BM * 32];
    __shared__ __align__(16) u16 Bs[2][BN * 32];
    const int tid = threadIdx.x;
    const int m0 = blockIdx.y * BM, n0 = blockIdx.x * BN;
    const int lane = tid & 63;
    const int wave = tid >> 6;
    const int wm = wave / WN, wn = wave % WN;
    const int lr = lane & 15, lk = lane >> 4;

    int kt0 = 0, kend = K;
    if (SPLITK > 1) {
        const int kb = K / SPLITK;
        kt0 = blockIdx.z * kb;
        kend = kt0 + kb;
        Cf += (size_t)blockIdx.z * zstride;
    }

    f32x4 acc[MR][NR];
#pragma unroll
    for (int m = 0; m < MR; ++m)
#pragma unroll
        for (int n = 0; n < NR; ++n) acc[m][n] = (f32x4){0.f, 0.f, 0.f, 0.f};

    auto stage = [&](int buf, int kt) {
#pragma unroll
        for (int c = 0; c < LA; ++c) {
            int idx = c * NT + tid;
            const u16* src = A + (size_t)(m0 + (idx >> 2)) * lda + kt + (idx & 3) * 8;
            __builtin_amdgcn_global_load_lds(
                (const __attribute__((address_space(1))) void*)src,
                (__attribute__((address_space(3))) void*)&As[buf][idx * 8], 16, 0, 0);
        }
#pragma unroll
        for (int c = 0; c < LB; ++c) {
            int idx = c * NT + tid;
            const u16* src = BT + (size_t)(n0 + (idx >> 2)) * ldb + kt + (idx & 3) * 8;
            __builtin_amdgcn_global_load_lds(
                (const __attribute__((address_space(1))) void*)src,
                (__attribute__((address_space(3))) void*)&Bs[buf][idx * 8], 16, 0, 0);
        }
    };

    stage(0, kt0);
    __syncthreads();
    int cur = 0;
    for (int kt = kt0; kt < kend; kt += 32) {
        if (kt + 32 < kend) stage(cur ^ 1, kt + 32);
        short8 a[MR], b[NR];
#pragma unroll
        for (int m = 0; m < MR; ++m)
            a[m] = *(const short8*)&As[cur][((wm * MR + m) * 16 + lr) * 32 + lk * 8];
#pragma unroll
        for (int n = 0; n < NR; ++n)
            b[n] = *(const short8*)&Bs[cur][((wn * NR + n) * 16 + lr) * 32 + lk * 8];
#pragma unroll
        for (int m = 0; m < MR; ++m)
#pragma unroll
            for (int n = 0; n < NR; ++n)
                acc[m][n] = mfma16(a[m], b[n], acc[m][n]);
        __syncthreads();
        cur ^= 1;
    }

#pragma unroll
    for (int m = 0; m < MR; ++m) {
#pragma unroll
        for (int n = 0; n < NR; ++n) {
#pragma unroll
            for (int r = 0; r < 4; ++r) {
                const int row = m0 + (wm * MR + m) * 16 + lk * 4 + r;
                const int col = n0 + (wn * NR + n) * 16 + lr;
                float v = acc[m][n][r];
                if (EPI == 1)      v += bias[col];
                else if (EPI == 2) v = gelu_exact(v + bias[col]);
                else if (EPI == 3) v = softplus_f(v + bias[col]);
                else if (EPI == 4) v += Cf[(size_t)row * ldc + col];
                if (Cf) Cf[(size_t)row * ldc + col] = v;
                if (Cb) Cb[(size_t)row * ldc + col] = f2bf(v);
            }
        }
    }
}

// transpose-cast: in (R,C) fp32 -> out (C,R) bf16; batched over blockIdx.z
__global__ __launch_bounds__(256) void tcast_k(const float* __restrict__ in, u16* __restrict__ out,
                                               int R, int C, size_t sin, size_t sout) {
    in  += (size_t)blockIdx.z * sin;
    out += (size_t)blockIdx.z * sout;
    __shared__ float s[32][33];
    const int tx = threadIdx.x & 31, ty = threadIdx.x >> 5;
    const int r0 = blockIdx.y * 32, c0 = blockIdx.x * 32;
#pragma unroll
    for (int i = 0; i < 4; ++i)
        s[ty + i * 8][tx] = in[(size_t)(r0 + ty + i * 8) * C + c0 + tx];
    __syncthreads();
#pragma unroll
    for (int i = 0; i < 4; ++i)
        out[(size_t)(c0 + ty + i * 8) * R + r0 + tx] = f2bf(s[tx][ty + i * 8]);
}

// strided cast+pad
__global__ void castpad_k(const float* __restrict__ in, u16* __restrict__ out,
                          int rows, int cin, int cout, int instride,
                          size_t sin, size_t sout) {
    in  += (size_t)blockIdx.z * sin;
    out += (size_t)blockIdx.z * sout;
    int idx = blockIdx.x * 256 + threadIdx.x;
    if (idx >= rows * cout) return;
    int c = idx % cout, r = idx / cout;
    out[idx] = (c < cin) ? f2bf(in[(size_t)r * instride + c]) : (u16)0;
}

// dwconv weight transpose: cw (nb,1024,4) -> cwT (nb,4,1024) f32
__global__ void cwt_k(const float* __restrict__ cw, float* __restrict__ cwT) {
    int idx = blockIdx.x * 256 + threadIdx.x;       // nb*4096
    if (idx >= NB * 4096) return;
    int z = idx >> 12, rem = idx & 4095;
    int d = rem >> 2, k = rem & 3;
    cwT[z * 4096 + k * 1024 + d] = cw[idx];
}

// im2col conv1 -> bf16 (K padded 240->256); also writes out_lens
__global__ void im2col1_k(const float* __restrict__ feats, u16* __restrict__ out,
                          const int* __restrict__ feat_lens, float* __restrict__ lens_out) {
    int idx = blockIdx.x * 256 + threadIdx.x;
    if (blockIdx.x == 0 && threadIdx.x < BATCH) {
        int v = feat_lens[threadIdx.x] / 4;
        if (v < 1) v = 1;
        lens_out[threadIdx.x] = (float)v;
    }
    int c = idx & 255, m = idx >> 8;
    int l1 = m & (LL1 - 1), b = m >> 10;
    float v = 0.f;
    if (c < 240) {
        int ci = c / 3, kk = c - ci * 3;
        int t = 2 * l1 - 1 + kk;
        if (t >= 0 && t < TIN) v = feats[((size_t)b * TIN + t) * MEL + ci];
    }
    out[idx] = f2bf(v);
}

// im2col conv2: bf16 in, bf16 out (2048,1536)
__global__ void im2col2_k(const u16* __restrict__ y1b, u16* __restrict__ out) {
    int idx = blockIdx.x * 256 + threadIdx.x;
    int c = idx % 1536, m = idx / 1536;
    int l = m & (LSEQ - 1), b = m >> 9;
    int ci = c / 3, kk = c - ci * 3;
    int t = 2 * l - 1 + kk;
    out[idx] = (t >= 0 && t < LL1) ? y1b[((size_t)b * LL1 + t) * 512 + ci] : (u16)0;
}

// RMSNorm: wave per row; fp32 in, bf16 out (R6-validated math)
__global__ __launch_bounds__(256) void rmsnorm_k(const float* __restrict__ X,
                                                 const float* __restrict__ nw,
                                                 u16* __restrict__ XN) {
    const int lane = threadIdx.x & 63;
    const int row = blockIdx.x * 4 + (threadIdx.x >> 6);
    const float4 v0 = *(const float4*)&X[(size_t)row * 512 + lane * 8];
    const float4 v1 = *(const float4*)&X[(size_t)row * 512 + lane * 8 + 4];
    float ss = v0.x * v0.x + v0.y * v0.y + v0.z * v0.z + v0.w * v0.w
             + v1.x * v1.x + v1.y * v1.y + v1.z * v1.z + v1.w * v1.w;
#pragma unroll
    for (int o = 1; o < 64; o <<= 1) ss += __shfl_xor(ss, o);
    const float sc = rsqrtf(ss * (1.f / 512.f) + 1e-5f);
    const float4 w0 = *(const float4*)&nw[lane * 8];
    const float4 w1 = *(const float4*)&nw[lane * 8 + 4];
    uint4 o4;
    o4.x = (u32)f2bf(v0.x * sc * w0.x) | ((u32)f2bf(v0.y * sc * w0.y) << 16);
    o4.y = (u32)f2bf(v0.z * sc * w0.z) | ((u32)f2bf(v0.w * sc * w0.w) << 16);
    o4.z = (u32)f2bf(v1.x * sc * w1.x) | ((u32)f2bf(v1.y * sc * w1.y) << 16);
    o4.w = (u32)f2bf(v1.z * sc * w1.z) | ((u32)f2bf(v1.w * sc * w1.w) << 16);
    *(uint4*)&XN[(size_t)row * 512 + lane * 8] = o4;
}

// ---------------------------------------------------------------------------
// Fused x-branch: dwconv+silu -> xs (LDS swizzled + global), x_proj MFMA
// (K=1024, B from global/L2), B/C cols -> XDB, dt cols -> LDS, dt_proj+
// softplus -> DELb.  Block = 16 rows, 4 waves.
// ---------------------------------------------------------------------------
__global__ __launch_bounds__(256) void fusedx_k(
    const u16* __restrict__ xzb, const float* __restrict__ cwT,
    const float* __restrict__ cb, const u16* __restrict__ xpwT,
    const u16* __restrict__ dpwT, const float* __restrict__ dpb,
    u16* __restrict__ xsb, float* __restrict__ xdb, u16* __restrict__ delb)
{
    __shared__ __align__(16) u16 xs_lds[16 * 1024];   // 32 KB, XOR-swizzled rows
    __shared__ float dt_lds[16][32];
    const int tid = threadIdx.x;
    const int r0 = blockIdx.x * 16;

    // phase A: dwconv + silu for 16 rows x 1024 d
#pragma unroll
    for (int it = 0; it < 8; ++it) {
        const int item = it * 256 + tid;
        const int row = item >> 7, cg = item & 127;
        const int m = r0 + row, l = m & (LSEQ - 1), b = m >> 9;
        const int d0 = cg * 8;
        float acc[8];
        const float4 cb0 = *(const float4*)&cb[d0];
        const float4 cb1 = *(const float4*)&cb[d0 + 4];
        acc[0] = cb0.x; acc[1] = cb0.y; acc[2] = cb0.z; acc[3] = cb0.w;
        acc[4] = cb1.x; acc[5] = cb1.y; acc[6] = cb1.z; acc[7] = cb1.w;
#pragma unroll
        for (int k = 0; k < 4; ++k) {
            const int t = l - 3 + k;
            if (t >= 0) {
                const short8 v = *(const short8*)&xzb[((size_t)(b * LSEQ + t)) * 2048 + d0];
                const float4 w0 = *(const float4*)&cwT[k * 1024 + d0];
                const float4 w1 = *(const float4*)&cwT[k * 1024 + d0 + 4];
                const float wv[8] = {w0.x, w0.y, w0.z, w0.w, w1.x, w1.y, w1.z, w1.w};
#pragma unroll
                for (int j = 0; j < 8; ++j)
                    acc[j] = fmaf(wv[j], bf2f((u16)v[j]), acc[j]);
            }
        }
        u32 pk[4];
#pragma unroll
        for (int j = 0; j < 4; ++j) {
            pk[j] = (u32)f2bf(silu_f(acc[2 * j])) | ((u32)f2bf(silu_f(acc[2 * j + 1])) << 16);
        }
        const uint4 pv = {pk[0], pk[1], pk[2], pk[3]};
        *(uint4*)((char*)xs_lds + row * 2048 + ((d0 * 2) ^ ((row & 7) << 4))) = pv;
        *(uint4*)&xsb[(size_t)m * 1024 + d0] = pv;
    }
    __syncthreads();

    // phase B: x_proj 16x64, K=1024.  wave w -> out cols [w*16, w*16+16)
    const int lane = tid & 63, w = tid >> 6;
    const int lr = lane & 15, lk = lane >> 4;
    f32x4 acc4 = (f32x4){0.f, 0.f, 0.f, 0.f};
    const u16* bptr = xpwT + (size_t)(w * 16 + lr) * 1024 + lk * 8;
    const char* aptr = (const char*)xs_lds + lr * 2048;
    const int axor = (lr & 7) << 4;
#pragma unroll 8
    for (int kt = 0; kt < 32; ++kt) {
        const short8 b8 = *(const short8*)(bptr + kt * 32);
        const short8 a8 = *(const short8*)(aptr + ((kt * 64 + lk * 16) ^ axor));
        acc4 = mfma16(a8, b8, acc4);
    }
    if (w >= 2) {
#pragma unroll
        for (int rr = 0; rr < 4; ++rr)
            xdb[(size_t)(r0 + lk * 4 + rr) * 64 + w * 16 + lr] = acc4[rr];
    } else {
#pragma unroll
        for (int rr = 0; rr < 4; ++rr)
            dt_lds[lk * 4 + rr][w * 16 + lr] = acc4[rr];
    }
    __syncthreads();

    // phase C: dt_proj + softplus -> DELb
#pragma unroll
    for (int i = 0; i < 4; ++i) {
        const int dcol = i * 256 + tid;
        const uint4 w0 = *(const uint4*)&dpwT[dcol * 32];
        const uint4 w1 = *(const uint4*)&dpwT[dcol * 32 + 8];
        const uint4 w2 = *(const uint4*)&dpwT[dcol * 32 + 16];
        const uint4 w3 = *(const uint4*)&dpwT[dcol * 32 + 24];
        const u32 wa[16] = {w0.x, w0.y, w0.z, w0.w, w1.x, w1.y, w1.z, w1.w,
                            w2.x, w2.y, w2.z, w2.w, w3.x, w3.y, w3.z, w3.w};
        float wk[32];
#pragma unroll
        for (int k = 0; k < 16; ++k) {
            wk[2 * k]     = bf2f((u16)(wa[k] & 0xffffu));
            wk[2 * k + 1] = bf2f((u16)(wa[k] >> 16));
        }
        const float bias = dpb[dcol];
#pragma unroll
        for (int r = 0; r < 16; ++r) {
            float acc = bias;
#pragma unroll
            for (int k = 0; k < 32; ++k) acc = fmaf(dt_lds[r][k], wk[k], acc);
            delb[(size_t)(r0 + r) * DIN + dcol] = f2bf(softplus_f(acc));
        }
    }
}

// ---------------------------------------------------------------------------
// Chunked parallel scan (R5-proven).
// ---------------------------------------------------------------------------
template<int PASS>
__global__ __launch_bounds__(256) void scan_chunk_k(
    const u16* __restrict__ deltab, const u16* __restrict__ xsb,
    const float* __restrict__ xdb, const u16* __restrict__ xzb,
    const float* __restrict__ alog, const float* __restrict__ dsk,
    float* __restrict__ P, float* __restrict__ Q,
    u16* __restrict__ yb)
{
    __shared__ float s_bc[LCHUNK * 32];
    __shared__ float s_dl[LCHUNK * 64];
    __shared__ float s_xs[LCHUNK * 64];
    __shared__ float s_z [PASS ? LCHUNK * 64 : 1];

    const int tid  = threadIdx.x;
    const int j    = tid & 3;
    const int dsub = tid >> 2;
    const int d0   = blockIdx.x * 64;
    const int c    = blockIdx.y;
    const int b    = blockIdx.z;
    const int d    = d0 + dsub;
    const size_t rbase = (size_t)b * LSEQ + c * LCHUNK;

    for (int idx = tid; idx < LCHUNK * 32; idx += 256) {
        int t = idx >> 5, cc = idx & 31;
        s_bc[idx] = xdb[(rbase + t) * 64 + 32 + cc];
    }
    for (int idx = tid; idx < LCHUNK * 64; idx += 256) {
        int t = idx >> 6, dd = idx & 63;
        s_dl[idx] = bf2f(deltab[(rbase + t) * DIN + d0 + dd]);
        s_xs[idx] = bf2f(xsb[(rbase + t) * DIN + d0 + dd]);
        if (PASS) s_z[idx] = bf2f(xzb[(rbase + t) * (2 * DIN) + DIN + d0 + dd]);
    }
    __syncthreads();

    float a[4], h[4];
#pragma unroll
    for (int nj = 0; nj < 4; nj++)
        a[nj] = -__expf(alog[(size_t)d * NSTATE + j * 4 + nj]);

    const size_t chstride = (size_t)DIN * NSTATE;
    const size_t chcol = (size_t)d * NSTATE + j * 4;
    h[0] = h[1] = h[2] = h[3] = 0.f;
    if (PASS) {
        for (int c2 = 0; c2 < c; ++c2) {
            const size_t o = ((size_t)(b * NCHUNK + c2)) * chstride + chcol;
            const float4 Pv = *(const float4*)&P[o];
            const float4 Qv = *(const float4*)&Q[o];
            h[0] = fmaf(Pv.x, h[0], Qv.x);
            h[1] = fmaf(Pv.y, h[1], Qv.y);
            h[2] = fmaf(Pv.z, h[2], Qv.z);
            h[3] = fmaf(Pv.w, h[3], Qv.w);
        }
    }
    const float dskv = PASS ? dsk[d] : 0.f;
    float sdl = 0.f;

    for (int t = 0; t < LCHUNK; t++) {
        const float dl = s_dl[t * 64 + dsub];
        const float xv = s_xs[t * 64 + dsub];
        const float dlx = dl * xv;
        if (!PASS) sdl += dl;
        float yv = 0.f;
#pragma unroll
        for (int nj = 0; nj < 4; nj++) {
            const float bn = s_bc[t * 32 + j * 4 + nj];
            const float dA = __expf(dl * a[nj]);
            h[nj] = fmaf(dA, h[nj], dlx * bn);
            if (PASS) {
                const float cn = s_bc[t * 32 + 16 + j * 4 + nj];
                yv = fmaf(h[nj], cn, yv);
            }
        }
        if (PASS) {
            yv += __shfl_xor(yv, 1);
            yv += __shfl_xor(yv, 2);
            if (j == 0) {
                const float zv = s_z[t * 64 + dsub];
                yb[(rbase + t) * DIN + d] = f2bf((yv + xv * dskv) * silu_f(zv));
            }
        }
    }

    if (!PASS) {
        const size_t o = ((size_t)(b * NCHUNK + c)) * chstride + chcol;
        float4 Pv, Qv;
        Pv.x = __expf(a[0] * sdl); Pv.y = __expf(a[1] * sdl);
        Pv.z = __expf(a[2] * sdl); Pv.w = __expf(a[3] * sdl);
        Qv.x = h[0]; Qv.y = h[1]; Qv.z = h[2]; Qv.w = h[3];
        *(float4*)&P[o] = Pv;
        *(float4*)&Q[o] = Qv;
    }
}

extern "C" void kernel_launch(void* const* d_in, const int* in_sizes, int n_in,
                              void* d_out, int out_size, void* d_ws, size_t ws_size,
                              hipStream_t stream)
{
    const float* feats = (const float*)d_in[0];
    const int*   flens = (const int*)  d_in[1];
    const float* c1w = (const float*)d_in[2];
    const float* c1b = (const float*)d_in[3];
    const float* c2w = (const float*)d_in[4];
    const float* c2b = (const float*)d_in[5];
    const float* nw  = (const float*)d_in[6];
    const float* ipw = (const float*)d_in[7];
    const float* cw  = (const float*)d_in[8];
    const float* cb  = (const float*)d_in[9];
    const float* xpw = (const float*)d_in[10];
    const float* dpw = (const float*)d_in[11];
    const float* dpb = (const float*)d_in[12];
    const float* alog= (const float*)d_in[13];
    const float* dskp= (const float*)d_in[14];
    const float* opw = (const float*)d_in[15];
    const float* hw  = (const float*)d_in[16];
    const float* hb  = (const float*)d_in[17];

    float* ws = (float*)d_ws;
    u16*  XZb    = (u16*)ws;                      // (2048,2048) bf16
    float* X     = ws + 2097152;                  // (2048,512) f32
    u16*  XN     = (u16*)(ws + 3145728);          // (2048,512) bf16
    u16*  Xb     = (u16*)(ws + 3670016);          // (2048,512) bf16
    u16*  XSb    = (u16*)(ws + 4194304);          // (2048,1024) bf16
    u16*  DELb   = (u16*)(ws + 5242880);          // (2048,1024) bf16
    float* XDB   = ws + 6291456;                  // (2048,64) f32
    float* P     = ws + 6422528;                  // (4,16,1024,16) f32
    u16*  Yb     = (u16*)(ws + 7503872);          // (2048,1024) bf16
    float* cwTa  = ws + 8552448;                  // 8 x (4,1024) f32
    u16*  ipwTa  = (u16*)(ws + 9076736);          // 8 x (2048,512) bf16
    u16*  opwTa  = (u16*)(ws + 13271040);         // 8 x (512,1024) bf16
    u16*  hwT    = (u16*)(ws + 15368192);         // (2048,512) bf16
    u16*  xpwT   = (u16*)(ws + 15892480);         // 8 x (64,1024) bf16
    u16*  dpwT   = (u16*)(ws + 16154624);         // 8 x (1024,32) bf16
    u16*  c1wb   = (u16*)(ws + 16285696);         // (512,256) bf16
    u16*  c2wb   = (u16*)(ws + 16351232);         // (512,1536) bf16
    u16*  Y1b    = (u16*)(ws + 16744448);         // (4096,512) bf16
    float* logits = (float*)d_out;
    float* Q     = logits;                        // 1M floats of d_out; head overwrites

    // ---------------- weight prep ----------------
    castpad_k<<<dim3(512, 1, 1), 256, 0, stream>>>(c1w, c1wb, 512, 240, 256, 240, 0, 0);
    castpad_k<<<dim3(3072, 1, 1), 256, 0, stream>>>(c2w, c2wb, 512, 1536, 1536, 1536, 0, 0);
    tcast_k<<<dim3(64, 16, 1), 256, 0, stream>>>(hw, hwT, 512, 2048, 0, 0);
    tcast_k<<<dim3(2, 32, 8), 256, 0, stream>>>(xpw, xpwT, 1024, 64, 65536, 65536);
    tcast_k<<<dim3(32, 1, 8), 256, 0, stream>>>(dpw, dpwT, 32, 1024, 32768, 32768);
    tcast_k<<<dim3(64, 16, 8), 256, 0, stream>>>(ipw, ipwTa, 512, 2048, 1048576, 1048576);
    tcast_k<<<dim3(16, 32, 8), 256, 0, stream>>>(opw, opwTa, 1024, 512, 524288, 524288);
    cwt_k<<<128, 256, 0, stream>>>(cw, cwTa);

    // ---------------- frontend ----------------
    im2col1_k<<<4096, 256, 0, stream>>>(feats, XZb, flens, logits + (size_t)MROWS * VOCABSZ);
    gemm2_bf16<2, 2, 4, 2, 2, 1><<<dim3(8, 32), 256, 0, stream>>>(
        XZb, 256, c1wb, 256, c1b, nullptr, Y1b, 512, 256, 0);
    im2col2_k<<<12288, 256, 0, stream>>>(Y1b, XZb);
    gemm2_bf16<2, 2, 2, 2, 2, 1><<<dim3(8, 32), 256, 0, stream>>>(
        XZb, 1536, c2wb, 1536, c2b, X, nullptr, 512, 1536, 0);

    // ---------------- mamba blocks ----------------
    for (int blk = 0; blk < NB; ++blk) {
        rmsnorm_k<<<512, 256, 0, stream>>>(X, nw + blk * DMODEL, XN);
        // in_proj (2048,2048,512), 128x64 tiles
        gemm2_bf16<2, 2, 4, 2, 0, 1><<<dim3(32, 16), 256, 0, stream>>>(
            XN, 512, ipwTa + (size_t)blk * 1048576, 512, nullptr,
            nullptr, XZb, 2048, 512, 0);
        // fused dwconv+silu + x_proj + dt_proj+softplus
        fusedx_k<<<128, 256, 0, stream>>>(
            XZb, cwTa + blk * 4096, cb + blk * DIN,
            xpwT + (size_t)blk * 65536, dpwT + (size_t)blk * 32768,
            dpb + blk * DIN, XSb, XDB, DELb);
        // chunked parallel scan
        scan_chunk_k<0><<<dim3(16, NCHUNK, BATCH), 256, 0, stream>>>(
            DELb, XSb, XDB, nullptr, alog + (size_t)blk * DIN * NSTATE,
            nullptr, P, Q, nullptr);
        scan_chunk_k<1><<<dim3(16, NCHUNK, BATCH), 256, 0, stream>>>(
            DELb, XSb, XDB, XZb, alog + (size_t)blk * DIN * NSTATE,
            dskp + blk * DIN, P, Q, Yb);
        // out_proj (2048,512,1024) + residual
        gemm2_bf16<2, 2, 2, 2, 4, 1><<<dim3(8, 32), 256, 0, stream>>>(
            Yb, 1024, opwTa + (size_t)blk * 524288, 1024, nullptr,
            X, Xb, 512, 1024, 0);
    }

    // ---------------- head (2048,2048,512), 128x64 tiles ----------------
    gemm2_bf16<2, 2, 4, 2, 1, 1><<<dim3(32, 16), 256, 0, stream>>>(
        Xb, 512, hwT, 512, hb, logits, nullptr, 2048, 512, 0);
}

// Round 9
// 885.133 us; speedup vs baseline: 5.9168x; 1.1075x over previous
//
#include <hip/hip_runtime.h>
#include <hip/hip_bf16.h>

#define DMODEL 512
#define NB 8
#define VOCABSZ 2048
#define MEL 80
#define DIN 1024
#define NSTATE 16
#define BATCH 4
#define TIN 2048
#define LL1 1024
#define LSEQ 512
#define MROWS (BATCH*LSEQ)    // 2048
#define M1ROWS (BATCH*LL1)    // 4096
#define NCHUNK 32
#define LCHUNK 16

typedef unsigned short u16;
typedef unsigned int   u32;
typedef __attribute__((ext_vector_type(8))) short short8;
typedef __attribute__((ext_vector_type(4))) float f32x4;

__device__ __forceinline__ float bf2f(u16 v) { return __uint_as_float(((u32)v) << 16); }
__device__ __forceinline__ u16 f2bf(float f) {
    u32 u = __float_as_uint(f);
    return (u16)((u + 0x7fffu + ((u >> 16) & 1u)) >> 16);
}
__device__ __forceinline__ float gelu_exact(float v) {
    return 0.5f * v * (1.0f + erff(v * 0.70710678118654752f));
}
__device__ __forceinline__ float silu_f(float v) { return v / (1.0f + __expf(-v)); }
__device__ __forceinline__ float softplus_f(float v) { return v > 20.f ? v : log1pf(__expf(v)); }

// ---------------------------------------------------------------------------
// bf16 MFMA GEMM, 2-phase double-buffered LDS (R5-proven).
// C[M,N] = epi(A[M,K] @ BT[N,K]^T + bias).  BM=WM*MR*16, BN=WN*NR*16, BK=32.
// EPI: 0 none, 1 +bias, 2 gelu(+bias), 3 softplus(+bias), 4 +=Cf residual,
//      6 row-scale (v *= bias[row])
// SPLITK>1: blockIdx.z owns K/SPLITK slice, writes Cf + z*zstride (EPI 0).
// ---------------------------------------------------------------------------
template<int WM, int WN, int MR, int NR, int EPI, int SPLITK>
__global__ __launch_bounds__(WM*WN*64) void gemm2_bf16(
    const u16* __restrict__ A, int lda,
    const u16* __restrict__ BT, int ldb,
    const float* __restrict__ bias,
    float* __restrict__ Cf, u16* __restrict__ Cb, int ldc,
    int K, int zstride)
{
    constexpr int BM = WM * MR * 16;
    constexpr int BN = WN * NR * 16;
    constexpr int NT = WM * WN * 64;
    constexpr int LA = (BM * 4) / NT;
    constexpr int LB = (BN * 4) / NT;
    __shared__ __align__(16) u16 As[2][BM * 32];
    __shared__ __align__(16) u16 Bs[2][BN * 32];
    const int tid = threadIdx.x;
    const int m0 = blockIdx.y * BM, n0 = blockIdx.x * BN;
    const int lane = tid & 63;
    const int wave = tid >> 6;
    const int wm = wave / WN, wn = wave % WN;
    const int lr = lane & 15, lk = lane >> 4;

    int kt0 = 0, kend = K;
    if (SPLITK > 1) {
        const int kb = K / SPLITK;
        kt0 = blockIdx.z * kb;
        kend = kt0 + kb;
        Cf += (size_t)blockIdx.z * zstride;
    }

    f32x4 acc[MR][NR];
#pragma unroll
    for (int m = 0; m < MR; ++m)
#pragma unroll
        for (int n = 0; n < NR; ++n) acc[m][n] = (f32x4){0.f, 0.f, 0.f, 0.f};

    auto stage = [&](int buf, int kt) {
#pragma unroll
        for (int c = 0; c < LA; ++c) {
            int idx = c * NT + tid;
            const u16* src = A + (size_t)(m0 + (idx >> 2)) * lda + kt + (idx & 3) * 8;
            __builtin_amdgcn_global_load_lds(
                (const __attribute__((address_space(1))) void*)src,
                (__attribute__((address_space(3))) void*)&As[buf][idx * 8], 16, 0, 0);
        }
#pragma unroll
        for (int c = 0; c < LB; ++c) {
            int idx = c * NT + tid;
            const u16* src = BT + (size_t)(n0 + (idx >> 2)) * ldb + kt + (idx & 3) * 8;
            __builtin_amdgcn_global_load_lds(
                (const __attribute__((address_space(1))) void*)src,
                (__attribute__((address_space(3))) void*)&Bs[buf][idx * 8], 16, 0, 0);
        }
    };

    stage(0, kt0);
    __syncthreads();
    int cur = 0;
    for (int kt = kt0; kt < kend; kt += 32) {
        if (kt + 32 < kend) stage(cur ^ 1, kt + 32);
        short8 a[MR], b[NR];
#pragma unroll
        for (int m = 0; m < MR; ++m)
            a[m] = *(const short8*)&As[cur][((wm * MR + m) * 16 + lr) * 32 + lk * 8];
#pragma unroll
        for (int n = 0; n < NR; ++n)
            b[n] = *(const short8*)&Bs[cur][((wn * NR + n) * 16 + lr) * 32 + lk * 8];
#pragma unroll
        for (int m = 0; m < MR; ++m)
#pragma unroll
            for (int n = 0; n < NR; ++n)
                acc[m][n] = __builtin_amdgcn_mfma_f32_16x16x32_bf16(a[m], b[n], acc[m][n], 0, 0, 0);
        __syncthreads();
        cur ^= 1;
    }

#pragma unroll
    for (int m = 0; m < MR; ++m) {
#pragma unroll
        for (int n = 0; n < NR; ++n) {
#pragma unroll
            for (int r = 0; r < 4; ++r) {
                const int row = m0 + (wm * MR + m) * 16 + lk * 4 + r;
                const int col = n0 + (wn * NR + n) * 16 + lr;
                float v = acc[m][n][r];
                if (EPI == 1)      v += bias[col];
                else if (EPI == 2) v = gelu_exact(v + bias[col]);
                else if (EPI == 3) v = softplus_f(v + bias[col]);
                else if (EPI == 4) v += Cf[(size_t)row * ldc + col];
                else if (EPI == 6) v *= bias[row];
                if (Cf) Cf[(size_t)row * ldc + col] = v;
                if (Cb) Cb[(size_t)row * ldc + col] = f2bf(v);
            }
        }
    }
}

// transpose-cast: in (R,C) fp32 -> out (C,R) bf16; batched over blockIdx.z
__global__ __launch_bounds__(256) void tcast_k(const float* __restrict__ in, u16* __restrict__ out,
                                               int R, int C, size_t sin, size_t sout) {
    in  += (size_t)blockIdx.z * sin;
    out += (size_t)blockIdx.z * sout;
    __shared__ float s[32][33];
    const int tx = threadIdx.x & 31, ty = threadIdx.x >> 5;
    const int r0 = blockIdx.y * 32, c0 = blockIdx.x * 32;
#pragma unroll
    for (int i = 0; i < 4; ++i)
        s[ty + i * 8][tx] = in[(size_t)(r0 + ty + i * 8) * C + c0 + tx];
    __syncthreads();
#pragma unroll
    for (int i = 0; i < 4; ++i)
        out[(size_t)(c0 + ty + i * 8) * R + r0 + tx] = f2bf(s[tx][ty + i * 8]);
}

// transpose-cast with per-ROW (K index) weight fold: out[c][r] = in[r][c]*nwp[r]
__global__ __launch_bounds__(256) void tcast_nw_k(const float* __restrict__ in, u16* __restrict__ out,
                                                  const float* __restrict__ nwp,
                                                  int R, int C, size_t sin, size_t sout, int nws) {
    in  += (size_t)blockIdx.z * sin;
    out += (size_t)blockIdx.z * sout;
    nwp += (size_t)blockIdx.z * nws;
    __shared__ float s[32][33];
    const int tx = threadIdx.x & 31, ty = threadIdx.x >> 5;
    const int r0 = blockIdx.y * 32, c0 = blockIdx.x * 32;
#pragma unroll
    for (int i = 0; i < 4; ++i)
        s[ty + i * 8][tx] = in[(size_t)(r0 + ty + i * 8) * C + c0 + tx];
    __syncthreads();
    const float nwv = nwp[r0 + tx];
#pragma unroll
    for (int i = 0; i < 4; ++i)
        out[(size_t)(c0 + ty + i * 8) * R + r0 + tx] = f2bf(s[tx][ty + i * 8] * nwv);
}

// strided cast+pad
__global__ void castpad_k(const float* __restrict__ in, u16* __restrict__ out,
                          int rows, int cin, int cout, int instride,
                          size_t sin, size_t sout) {
    in  += (size_t)blockIdx.z * sin;
    out += (size_t)blockIdx.z * sout;
    int idx = blockIdx.x * 256 + threadIdx.x;
    if (idx >= rows * cout) return;
    int c = idx % cout, r = idx / cout;
    out[idx] = (c < cin) ? f2bf(in[(size_t)r * instride + c]) : (u16)0;
}

// im2col conv1 -> bf16 (K padded 240->256); also writes out_lens
__global__ void im2col1_k(const float* __restrict__ feats, u16* __restrict__ out,
                          const int* __restrict__ feat_lens, float* __restrict__ lens_out) {
    int idx = blockIdx.x * 256 + threadIdx.x;
    if (blockIdx.x == 0 && threadIdx.x < BATCH) {
        int v = feat_lens[threadIdx.x] / 4;
        if (v < 1) v = 1;
        lens_out[threadIdx.x] = (float)v;
    }
    int c = idx & 255, m = idx >> 8;
    int l1 = m & (LL1 - 1), b = m >> 10;
    float v = 0.f;
    if (c < 240) {
        int ci = c / 3, kk = c - ci * 3;
        int t = 2 * l1 - 1 + kk;
        if (t >= 0 && t < TIN) v = feats[((size_t)b * TIN + t) * MEL + ci];
    }
    out[idx] = f2bf(v);
}

// im2col conv2: bf16 in, bf16 out (2048,1536)
__global__ void im2col2_k(const u16* __restrict__ y1b, u16* __restrict__ out) {
    int idx = blockIdx.x * 256 + threadIdx.x;
    int c = idx % 1536, m = idx / 1536;
    int l = m & (LSEQ - 1), b = m >> 9;
    int ci = c / 3, kk = c - ci * 3;
    int t = 2 * l - 1 + kk;
    out[idx] = (t >= 0 && t < LL1) ? y1b[((size_t)b * LL1 + t) * 512 + ci] : (u16)0;
}

// row 1/rms scale: wave per row (4 rows / block)
__global__ __launch_bounds__(256) void rowsc_k(const float* __restrict__ X,
                                               float* __restrict__ scrow) {
    const int lane = threadIdx.x & 63;
    const int row = blockIdx.x * 4 + (threadIdx.x >> 6);
    const float4 v0 = *(const float4*)&X[(size_t)row * 512 + lane * 8];
    const float4 v1 = *(const float4*)&X[(size_t)row * 512 + lane * 8 + 4];
    float ss = v0.x * v0.x + v0.y * v0.y + v0.z * v0.z + v0.w * v0.w
             + v1.x * v1.x + v1.y * v1.y + v1.z * v1.z + v1.w * v1.w;
#pragma unroll
    for (int o = 1; o < 64; o <<= 1) ss += __shfl_xor(ss, o);
    if (lane == 0) scrow[row] = rsqrtf(ss * (1.f / 512.f) + 1e-5f);
}

// causal depthwise conv (K=4) + bias + SiLU; bf16 in, bf16 out
__global__ __launch_bounds__(256) void dwconv_silu_k(const u16* __restrict__ xzb,
                                                     const float* __restrict__ cw,
                                                     const float* __restrict__ cb,
                                                     u16* __restrict__ xsb) {
    int d = blockIdx.x * 256 + threadIdx.x;
    int m = blockIdx.y;
    int l = m & (LSEQ - 1);
    int b = m >> 9;
    float acc = cb[d];
    const float4 w4 = *reinterpret_cast<const float4*>(&cw[d * 4]);
    const float wk[4] = {w4.x, w4.y, w4.z, w4.w};
#pragma unroll
    for (int k = 0; k < 4; k++) {
        int t = l - 3 + k;
        if (t >= 0) acc += wk[k] * bf2f(xzb[((size_t)(b * LSEQ + t)) * (2 * DIN) + d]);
    }
    xsb[(size_t)m * DIN + d] = f2bf(silu_f(acc));
}

// split-K reduce for x_proj (vectorized): sum 4 partials -> XDB f32; cols<32 -> dtb bf16
__global__ void xreduce_k(const float* __restrict__ part, float* __restrict__ xdb,
                          u16* __restrict__ dtb) {
    int i4 = blockIdx.x * 256 + threadIdx.x;        // 32768
    const float4 p0 = *(const float4*)&part[i4 * 4];
    const float4 p1 = *(const float4*)&part[131072 + i4 * 4];
    const float4 p2 = *(const float4*)&part[262144 + i4 * 4];
    const float4 p3 = *(const float4*)&part[393216 + i4 * 4];
    float4 s;
    s.x = p0.x + p1.x + p2.x + p3.x;
    s.y = p0.y + p1.y + p2.y + p3.y;
    s.z = p0.z + p1.z + p2.z + p3.z;
    s.w = p0.w + p1.w + p2.w + p3.w;
    *(float4*)&xdb[i4 * 4] = s;
    int c4 = i4 & 15, r = i4 >> 4;
    if (c4 < 8) {
        u32 lo = (u32)f2bf(s.x) | ((u32)f2bf(s.y) << 16);
        u32 hi = (u32)f2bf(s.z) | ((u32)f2bf(s.w) << 16);
        *(u32*)&dtb[r * 32 + c4 * 4]     = lo;
        *(u32*)&dtb[r * 32 + c4 * 4 + 2] = hi;
    }
}

// ---------------------------------------------------------------------------
// Chunked parallel scan, NCHUNK=32 / LCHUNK=16.
// PASS0: emit P,Q.  PASS1: combine prefix in-kernel, seeded scan, fused
// +xs*D and *silu(z) epilogue -> y bf16.
// ---------------------------------------------------------------------------
template<int PASS>
__global__ __launch_bounds__(256) void scan_chunk_k(
    const u16* __restrict__ deltab, const u16* __restrict__ xsb,
    const float* __restrict__ xdb, const u16* __restrict__ xzb,
    const float* __restrict__ alog, const float* __restrict__ dsk,
    float* __restrict__ P, float* __restrict__ Q,
    u16* __restrict__ yb)
{
    __shared__ float s_bc[LCHUNK * 32];
    __shared__ float s_dl[LCHUNK * 64];
    __shared__ float s_xs[LCHUNK * 64];
    __shared__ float s_z [PASS ? LCHUNK * 64 : 1];

    const int tid  = threadIdx.x;
    const int j    = tid & 3;
    const int dsub = tid >> 2;
    const int d0   = blockIdx.x * 64;
    const int c    = blockIdx.y;
    const int b    = blockIdx.z;
    const int d    = d0 + dsub;
    const size_t rbase = (size_t)b * LSEQ + c * LCHUNK;

    for (int idx = tid; idx < LCHUNK * 32; idx += 256) {
        int t = idx >> 5, cc = idx & 31;
        s_bc[idx] = xdb[(rbase + t) * 64 + 32 + cc];
    }
    for (int idx = tid; idx < LCHUNK * 64; idx += 256) {
        int t = idx >> 6, dd = idx & 63;
        s_dl[idx] = bf2f(deltab[(rbase + t) * DIN + d0 + dd]);
        s_xs[idx] = bf2f(xsb[(rbase + t) * DIN + d0 + dd]);
        if (PASS) s_z[idx] = bf2f(xzb[(rbase + t) * (2 * DIN) + DIN + d0 + dd]);
    }
    __syncthreads();

    float a[4], h[4];
#pragma unroll
    for (int nj = 0; nj < 4; nj++)
        a[nj] = -__expf(alog[(size_t)d * NSTATE + j * 4 + nj]);

    const size_t chstride = (size_t)DIN * NSTATE;
    const size_t chcol = (size_t)d * NSTATE + j * 4;
    h[0] = h[1] = h[2] = h[3] = 0.f;
    if (PASS) {
        for (int c2 = 0; c2 < c; ++c2) {
            const size_t o = ((size_t)(b * NCHUNK + c2)) * chstride + chcol;
            const float4 Pv = *(const float4*)&P[o];
            const float4 Qv = *(const float4*)&Q[o];
            h[0] = fmaf(Pv.x, h[0], Qv.x);
            h[1] = fmaf(Pv.y, h[1], Qv.y);
            h[2] = fmaf(Pv.z, h[2], Qv.z);
            h[3] = fmaf(Pv.w, h[3], Qv.w);
        }
    }
    const float dskv = PASS ? dsk[d] : 0.f;
    float sdl = 0.f;

    for (int t = 0; t < LCHUNK; t++) {
        const float dl = s_dl[t * 64 + dsub];
        const float xv = s_xs[t * 64 + dsub];
        const float dlx = dl * xv;
        if (!PASS) sdl += dl;
        float yv = 0.f;
#pragma unroll
        for (int nj = 0; nj < 4; nj++) {
            const float bn = s_bc[t * 32 + j * 4 + nj];
            const float dA = __expf(dl * a[nj]);
            h[nj] = fmaf(dA, h[nj], dlx * bn);
            if (PASS) {
                const float cn = s_bc[t * 32 + 16 + j * 4 + nj];
                yv = fmaf(h[nj], cn, yv);
            }
        }
        if (PASS) {
            yv += __shfl_xor(yv, 1);
            yv += __shfl_xor(yv, 2);
            if (j == 0) {
                const float zv = s_z[t * 64 + dsub];
                yb[(rbase + t) * DIN + d] = f2bf((yv + xv * dskv) * silu_f(zv));
            }
        }
    }

    if (!PASS) {
        const size_t o = ((size_t)(b * NCHUNK + c)) * chstride + chcol;
        float4 Pv, Qv;
        Pv.x = __expf(a[0] * sdl); Pv.y = __expf(a[1] * sdl);
        Pv.z = __expf(a[2] * sdl); Pv.w = __expf(a[3] * sdl);
        Qv.x = h[0]; Qv.y = h[1]; Qv.z = h[2]; Qv.w = h[3];
        *(float4*)&P[o] = Pv;
        *(float4*)&Q[o] = Qv;
    }
}

extern "C" void kernel_launch(void* const* d_in, const int* in_sizes, int n_in,
                              void* d_out, int out_size, void* d_ws, size_t ws_size,
                              hipStream_t stream)
{
    const float* feats = (const float*)d_in[0];
    const int*   flens = (const int*)  d_in[1];
    const float* c1w = (const float*)d_in[2];
    const float* c1b = (const float*)d_in[3];
    const float* c2w = (const float*)d_in[4];
    const float* c2b = (const float*)d_in[5];
    const float* nw  = (const float*)d_in[6];
    const float* ipw = (const float*)d_in[7];
    const float* cw  = (const float*)d_in[8];
    const float* cb  = (const float*)d_in[9];
    const float* xpw = (const float*)d_in[10];
    const float* dpw = (const float*)d_in[11];
    const float* dpb = (const float*)d_in[12];
    const float* alog= (const float*)d_in[13];
    const float* dskp= (const float*)d_in[14];
    const float* opw = (const float*)d_in[15];
    const float* hw  = (const float*)d_in[16];
    const float* hb  = (const float*)d_in[17];

    float* ws = (float*)d_ws;
    u16*  XZb    = (u16*)ws;                      // (2048,2048) bf16
    float* X     = ws + 2097152;                  // (2048,512) f32
    u16*  Xb     = (u16*)(ws + 3145728);          // (2048,512) bf16
    float* scrow = ws + 3670016;                  // 2048 f32
    u16*  XSb    = (u16*)(ws + 4194304);          // (2048,1024) bf16 ; Y1b alias
    u16*  DELb   = (u16*)(ws + 5242880);          // (2048,1024) bf16
    float* XDB   = ws + 6291456;                  // (2048,64) f32
    u16*  dtb    = (u16*)(ws + 6422528);          // (2048,32) bf16
    float* P     = ws + 6455296;                  // (4,32,1024,16) f32 = 2M f
    u16*  Yb     = (u16*)(ws + 8552448);          // (2048,1024) bf16
    float* XDBp  = ws + 9601024;                  // 4 x (2048,64) f32
    u16*  ipwTa  = (u16*)(ws + 10125312);         // 8 x (2048,512) bf16 (nw-folded)
    u16*  opwTa  = (u16*)(ws + 14319616);         // 8 x (512,1024) bf16
    u16*  hwT    = (u16*)(ws + 16416768);         // (2048,512) bf16
    u16*  xpwT   = (u16*)(ws + 16941056);         // 8 x (64,1024) bf16
    u16*  dpwT   = (u16*)(ws + 17203200);         // 8 x (1024,32) bf16
    u16*  c1wb   = (u16*)(ws + 17334272);         // (512,256) bf16
    u16*  c2wb   = (u16*)(ws + 17399808);         // (512,1536) bf16
    u16*  Y1b    = XSb;                           // frontend-only alias
    float* logits = (float*)d_out;
    float* Q     = logits;                        // 2M floats of d_out; head overwrites

    // ---------------- weight prep (once, batched) ----------------
    castpad_k<<<dim3(512, 1, 1), 256, 0, stream>>>(c1w, c1wb, 512, 240, 256, 240, 0, 0);
    castpad_k<<<dim3(3072, 1, 1), 256, 0, stream>>>(c2w, c2wb, 512, 1536, 1536, 1536, 0, 0);
    tcast_k<<<dim3(64, 16, 1), 256, 0, stream>>>(hw, hwT, 512, 2048, 0, 0);
    tcast_k<<<dim3(2, 32, 8), 256, 0, stream>>>(xpw, xpwT, 1024, 64, 65536, 65536);
    tcast_k<<<dim3(32, 1, 8), 256, 0, stream>>>(dpw, dpwT, 32, 1024, 32768, 32768);
    tcast_nw_k<<<dim3(64, 16, 8), 256, 0, stream>>>(ipw, ipwTa, nw, 512, 2048,
                                                    1048576, 1048576, DMODEL);
    tcast_k<<<dim3(16, 32, 8), 256, 0, stream>>>(opw, opwTa, 1024, 512, 524288, 524288);

    // ---------------- frontend ----------------
    im2col1_k<<<4096, 256, 0, stream>>>(feats, XZb, flens, logits + (size_t)MROWS * VOCABSZ);
    gemm2_bf16<2, 2, 4, 2, 2, 1><<<dim3(8, 32), 256, 0, stream>>>(
        XZb, 256, c1wb, 256, c1b, nullptr, Y1b, 512, 256, 0);
    im2col2_k<<<12288, 256, 0, stream>>>(Y1b, XZb);
    gemm2_bf16<2, 2, 2, 2, 2, 1><<<dim3(8, 32), 256, 0, stream>>>(
        XZb, 1536, c2wb, 1536, c2b, X, Xb, 512, 1536, 0);

    // ---------------- mamba blocks ----------------
    for (int blk = 0; blk < NB; ++blk) {
        rowsc_k<<<512, 256, 0, stream>>>(X, scrow);
        // in_proj: (2048,2048,512), A=Xb, epilogue x sc[row] (nw folded in weights)
        gemm2_bf16<2, 2, 4, 2, 6, 1><<<dim3(32, 16), 256, 0, stream>>>(
            Xb, 512, ipwTa + (size_t)blk * 1048576, 512, scrow,
            nullptr, XZb, 2048, 512, 0);
        dwconv_silu_k<<<dim3(4, MROWS), 256, 0, stream>>>(
            XZb, cw + blk * DIN * 4, cb + blk * DIN, XSb);
        // x_proj: (2048,64,1024) split-K x4
        gemm2_bf16<2, 2, 2, 2, 0, 4><<<dim3(1, 32, 4), 256, 0, stream>>>(
            XSb, 1024, xpwT + (size_t)blk * 65536, 1024, nullptr,
            XDBp, nullptr, 64, 1024, 131072);
        xreduce_k<<<128, 256, 0, stream>>>(XDBp, XDB, dtb);
        // dt_proj: (2048,1024,32) + softplus
        gemm2_bf16<2, 2, 4, 2, 3, 1><<<dim3(16, 16), 256, 0, stream>>>(
            dtb, 32, dpwT + (size_t)blk * 32768, 32, dpb + blk * DIN,
            nullptr, DELb, 1024, 32, 0);
        // chunked parallel scan (NCHUNK=32, LCHUNK=16)
        scan_chunk_k<0><<<dim3(16, NCHUNK, BATCH), 256, 0, stream>>>(
            DELb, XSb, XDB, nullptr, alog + (size_t)blk * DIN * NSTATE,
            nullptr, P, Q, nullptr);
        scan_chunk_k<1><<<dim3(16, NCHUNK, BATCH), 256, 0, stream>>>(
            DELb, XSb, XDB, XZb, alog + (size_t)blk * DIN * NSTATE,
            dskp + blk * DIN, P, Q, Yb);
        // out_proj: (2048,512,1024) + residual -> X f32 + Xb bf16
        gemm2_bf16<2, 2, 2, 2, 4, 1><<<dim3(8, 32), 256, 0, stream>>>(
            Yb, 1024, opwTa + (size_t)blk * 524288, 1024, nullptr,
            X, Xb, 512, 1024, 0);
    }

    // ---------------- head: (2048,2048,512) ----------------
    gemm2_bf16<2, 2, 4, 2, 1, 1><<<dim3(32, 16), 256, 0, stream>>>(
        Xb, 512, hwT, 512, hb, logits, nullptr, 2048, 512, 0);
}